// Round 1
// baseline (99.804 us; speedup 1.0000x reference)
//
#include <hip/hip_runtime.h>
#include <math.h>

#define HIDDEN 128
#define NGRAPH 16384
#define TWOH 256

// shifted-softplus shift = log(2)
__device__ __constant__ float kSHIFT = 0.69314718055994530942f;

// ---------------------------------------------------------------------------
// Kernel 1: segment-sum readout. batch is SORTED, so graph g's nodes occupy a
// contiguous range [start,end) found by binary search. One block per graph,
// 128 threads: thread t owns float4 column (t&31), row-lane (t>>5) strides by 4.
// Coalesced float4 streaming of v; zero atomics; empty graphs write zeros
// (so u needs no separate memset).
// ---------------------------------------------------------------------------
__global__ __launch_bounds__(128) void seg_sum_kernel(
    const float* __restrict__ v, const int* __restrict__ batch,
    float* __restrict__ u, int n_nodes)
{
    const int g = blockIdx.x;

    // lower_bound(batch, g) and lower_bound(batch, g+1) — uniform across block
    int lo = 0, hi = n_nodes;
    while (lo < hi) { int mid = (lo + hi) >> 1; if (batch[mid] < g) lo = mid + 1; else hi = mid; }
    const int start = lo;
    hi = n_nodes;
    while (lo < hi) { int mid = (lo + hi) >> 1; if (batch[mid] < g + 1) lo = mid + 1; else hi = mid; }
    const int end = lo;

    const int t  = threadIdx.x;
    const int f4 = t & 31;   // which float4 of the 32 per row
    const int ro = t >> 5;   // row lane 0..3

    float4 acc = make_float4(0.f, 0.f, 0.f, 0.f);
    const float4* __restrict__ v4 = reinterpret_cast<const float4*>(v);
    for (int r = start + ro; r < end; r += 4) {
        float4 x = v4[(size_t)r * 32 + f4];
        acc.x += x.x; acc.y += x.y; acc.z += x.z; acc.w += x.w;
    }

    __shared__ float4 red[128];
    red[t] = acc;
    __syncthreads();
    if (t < 32) {
        float4 a0 = red[t], a1 = red[t + 32], a2 = red[t + 64], a3 = red[t + 96];
        float4 s;
        s.x = (a0.x + a1.x) + (a2.x + a3.x);
        s.y = (a0.y + a1.y) + (a2.y + a3.y);
        s.z = (a0.z + a1.z) + (a2.z + a3.z);
        s.w = (a0.w + a1.w) + (a2.w + a3.w);
        reinterpret_cast<float4*>(u)[(size_t)g * 32 + t] = s;
    }
}

// ---------------------------------------------------------------------------
// Kernel 2: fused MLP. out[g] = b2 + sum_c (softplus(u[g]·W1[:,c] + b1[c]) - SHIFT) * W2[c]
// Tall-skinny GEMM M=16384 K=128 N=256. Tile: 64 rows/block, 256 threads,
// 8x8 register blocking. u tile (32KB) + W1 K-chunk (32KB) in LDS.
// Thread t: rows (t>>5)+8i, cols (t&31)+32j  (i,j in 0..7).
// a-loads: per-wave 2 distinct addrs (broadcast, free). b-loads: lane-
// consecutive stride-4B (2-way alias across 64 lanes = free).
// ---------------------------------------------------------------------------
__global__ __launch_bounds__(256) void mlp_kernel(
    const float* __restrict__ u, const float* __restrict__ W1,
    const float* __restrict__ b1, const float* __restrict__ W2,
    const float* __restrict__ b2, float* __restrict__ out)
{
    __shared__ float u_s[64 * 128];   // 32 KB
    __shared__ float w_s[32 * 256];   // 32 KB

    const int t = threadIdx.x;
    const int row0 = blockIdx.x * 64;
    const int cg = t & 31;   // col group
    const int rg = t >> 5;   // row group

    // stage u tile: contiguous copy, coalesced
    #pragma unroll
    for (int s = 0; s < 32; ++s) {
        int idx = t + 256 * s;
        u_s[idx] = u[(size_t)row0 * 128 + idx];
    }

    float acc[8][8];
    #pragma unroll
    for (int i = 0; i < 8; ++i)
        #pragma unroll
        for (int j = 0; j < 8; ++j) acc[i][j] = 0.f;

    for (int kc = 0; kc < 4; ++kc) {
        __syncthreads();  // covers u_s on first iter, w_s reuse on later iters
        #pragma unroll
        for (int s = 0; s < 32; ++s) {
            int idx = t + 256 * s;
            w_s[idx] = W1[kc * 32 * 256 + idx];
        }
        __syncthreads();

        #pragma unroll 4
        for (int k = 0; k < 32; ++k) {
            float a[8], b[8];
            #pragma unroll
            for (int i = 0; i < 8; ++i) a[i] = u_s[(rg + 8 * i) * 128 + kc * 32 + k];
            #pragma unroll
            for (int j = 0; j < 8; ++j) b[j] = w_s[k * 256 + cg + 32 * j];
            #pragma unroll
            for (int i = 0; i < 8; ++i)
                #pragma unroll
                for (int j = 0; j < 8; ++j)
                    acc[i][j] = fmaf(a[i], b[j], acc[i][j]);
        }
    }

    // epilogue: bias, shifted softplus, W2 contraction, 32-lane reduce
    const float bias2 = b2[0];
    #pragma unroll
    for (int i = 0; i < 8; ++i) {
        float partial = 0.f;
        #pragma unroll
        for (int j = 0; j < 8; ++j) {
            int c = cg + 32 * j;
            float x = acc[i][j] + b1[c];
            // numerically stable softplus: max(x,0) + log1p(exp(-|x|))
            float h = fmaxf(x, 0.f) + log1pf(expf(-fabsf(x))) - kSHIFT;
            partial += h * W2[c];
        }
        #pragma unroll
        for (int m = 16; m >= 1; m >>= 1)
            partial += __shfl_xor(partial, m);
        if (cg == 0)
            out[row0 + rg + 8 * i] = partial + bias2;
    }
}

extern "C" void kernel_launch(void* const* d_in, const int* in_sizes, int n_in,
                              void* d_out, int out_size, void* d_ws, size_t ws_size,
                              hipStream_t stream) {
    const float* v     = (const float*)d_in[0];
    const int*   batch = (const int*)d_in[1];   // harness converts integer inputs to int32
    const float* W1    = (const float*)d_in[2];
    const float* b1    = (const float*)d_in[3];
    const float* W2    = (const float*)d_in[4];
    const float* b2    = (const float*)d_in[5];
    float* out = (float*)d_out;

    const int n_nodes = in_sizes[0] / HIDDEN;   // 500000
    float* u = (float*)d_ws;                    // 16384*128*4 = 8 MB scratch

    seg_sum_kernel<<<NGRAPH, 128, 0, stream>>>(v, batch, u, n_nodes);
    mlp_kernel<<<NGRAPH / 64, 256, 0, stream>>>(u, W1, b1, W2, b2, out);
}

// Round 2
// 86.398 us; speedup vs baseline: 1.1552x; 1.1552x over previous
//
#include <hip/hip_runtime.h>
#include <math.h>

#define HIDDEN 128
#define NGRAPH 16384
#define TWOH 256

// shifted-softplus shift = log(2)
__device__ __constant__ float kSHIFT = 0.69314718055994530942f;

// ---------------------------------------------------------------------------
// Kernel 0: boundary scan. batch is sorted; thread i detects a segment
// boundary (batch[i] != batch[i-1]) and writes offs[g] = i for every graph g
// starting at i (covers empty graphs). offs[NGRAPH] = n_nodes.
// One coalesced pass over batch (2 MB) — replaces 16384 x 2 binary searches
// (38 dependent L2 loads each) in the seg-sum kernel.
// ---------------------------------------------------------------------------
__global__ __launch_bounds__(256) void offsets_kernel(
    const int* __restrict__ batch, int* __restrict__ offs, int n_nodes)
{
    int i = blockIdx.x * blockDim.x + threadIdx.x;
    if (i >= n_nodes) return;
    int b = batch[i];
    int prev = (i == 0) ? -1 : batch[i - 1];
    for (int g = prev + 1; g <= b; ++g) offs[g] = i;        // rare (16384/500k)
    if (i == n_nodes - 1) {
        for (int g = b + 1; g <= NGRAPH; ++g) offs[g] = n_nodes;
    }
}

// ---------------------------------------------------------------------------
// Kernel 1: segment-sum readout. Graph g's rows are [offs[g], offs[g+1]).
// One block per graph, 128 threads: thread t owns float4 column (t&31),
// row-lane (t>>5) strides by 4. Each wave reads 2 full contiguous rows
// (1 KiB) per iteration — perfectly coalesced. Empty graphs write zeros.
// ---------------------------------------------------------------------------
__global__ __launch_bounds__(128) void seg_sum_kernel(
    const float* __restrict__ v, const int* __restrict__ offs,
    float* __restrict__ u)
{
    const int g = blockIdx.x;
    const int start = offs[g];
    const int end   = offs[g + 1];

    const int t  = threadIdx.x;
    const int f4 = t & 31;   // which float4 of the 32 per row
    const int ro = t >> 5;   // row lane 0..3

    float4 acc = make_float4(0.f, 0.f, 0.f, 0.f);
    const float4* __restrict__ v4 = reinterpret_cast<const float4*>(v);
    for (int r = start + ro; r < end; r += 4) {
        float4 x = v4[(size_t)r * 32 + f4];
        acc.x += x.x; acc.y += x.y; acc.z += x.z; acc.w += x.w;
    }

    __shared__ float4 red[128];
    red[t] = acc;
    __syncthreads();
    if (t < 32) {
        float4 a0 = red[t], a1 = red[t + 32], a2 = red[t + 64], a3 = red[t + 96];
        float4 s;
        s.x = (a0.x + a1.x) + (a2.x + a3.x);
        s.y = (a0.y + a1.y) + (a2.y + a3.y);
        s.z = (a0.z + a1.z) + (a2.z + a3.z);
        s.w = (a0.w + a1.w) + (a2.w + a3.w);
        reinterpret_cast<float4*>(u)[(size_t)g * 32 + t] = s;
    }
}

// ---------------------------------------------------------------------------
// Kernel 2: fused MLP. out[g] = b2 + sum_c (softplus(u[g]·W1[:,c] + b1[c]) - SHIFT) * W2[c]
// Tall-skinny GEMM M=16384 K=128 N=256. Tile: 64 rows/block, 256 threads,
// 8x8 register blocking. u tile (32KB) + W1 K-chunk (32KB) in LDS.
// ---------------------------------------------------------------------------
__global__ __launch_bounds__(256) void mlp_kernel(
    const float* __restrict__ u, const float* __restrict__ W1,
    const float* __restrict__ b1, const float* __restrict__ W2,
    const float* __restrict__ b2, float* __restrict__ out)
{
    __shared__ float u_s[64 * 128];   // 32 KB
    __shared__ float w_s[32 * 256];   // 32 KB

    const int t = threadIdx.x;
    const int row0 = blockIdx.x * 64;
    const int cg = t & 31;   // col group
    const int rg = t >> 5;   // row group

    // stage u tile: contiguous copy, coalesced
    #pragma unroll
    for (int s = 0; s < 32; ++s) {
        int idx = t + 256 * s;
        u_s[idx] = u[(size_t)row0 * 128 + idx];
    }

    float acc[8][8];
    #pragma unroll
    for (int i = 0; i < 8; ++i)
        #pragma unroll
        for (int j = 0; j < 8; ++j) acc[i][j] = 0.f;

    for (int kc = 0; kc < 4; ++kc) {
        __syncthreads();  // covers u_s on first iter, w_s reuse on later iters
        #pragma unroll
        for (int s = 0; s < 32; ++s) {
            int idx = t + 256 * s;
            w_s[idx] = W1[kc * 32 * 256 + idx];
        }
        __syncthreads();

        #pragma unroll 4
        for (int k = 0; k < 32; ++k) {
            float a[8], b[8];
            #pragma unroll
            for (int i = 0; i < 8; ++i) a[i] = u_s[(rg + 8 * i) * 128 + kc * 32 + k];
            #pragma unroll
            for (int j = 0; j < 8; ++j) b[j] = w_s[k * 256 + cg + 32 * j];
            #pragma unroll
            for (int i = 0; i < 8; ++i)
                #pragma unroll
                for (int j = 0; j < 8; ++j)
                    acc[i][j] = fmaf(a[i], b[j], acc[i][j]);
        }
    }

    // epilogue: bias, shifted softplus, W2 contraction, 32-lane reduce
    const float bias2 = b2[0];
    #pragma unroll
    for (int i = 0; i < 8; ++i) {
        float partial = 0.f;
        #pragma unroll
        for (int j = 0; j < 8; ++j) {
            int c = cg + 32 * j;
            float x = acc[i][j] + b1[c];
            // numerically stable softplus: max(x,0) + log1p(exp(-|x|))
            float h = fmaxf(x, 0.f) + log1pf(expf(-fabsf(x))) - kSHIFT;
            partial += h * W2[c];
        }
        #pragma unroll
        for (int m = 16; m >= 1; m >>= 1)
            partial += __shfl_xor(partial, m);
        if (cg == 0)
            out[row0 + rg + 8 * i] = partial + bias2;
    }
}

extern "C" void kernel_launch(void* const* d_in, const int* in_sizes, int n_in,
                              void* d_out, int out_size, void* d_ws, size_t ws_size,
                              hipStream_t stream) {
    const float* v     = (const float*)d_in[0];
    const int*   batch = (const int*)d_in[1];   // harness converts integer inputs to int32
    const float* W1    = (const float*)d_in[2];
    const float* b1    = (const float*)d_in[3];
    const float* W2    = (const float*)d_in[4];
    const float* b2    = (const float*)d_in[5];
    float* out = (float*)d_out;

    const int n_nodes = in_sizes[0] / HIDDEN;   // 500000

    float* u   = (float*)d_ws;                                   // 8 MB
    int*   offs = (int*)((char*)d_ws + (size_t)NGRAPH * HIDDEN * 4); // 64 KB + 4

    offsets_kernel<<<(n_nodes + 255) / 256, 256, 0, stream>>>(batch, offs, n_nodes);
    seg_sum_kernel<<<NGRAPH, 128, 0, stream>>>(v, offs, u);
    mlp_kernel<<<NGRAPH / 64, 256, 0, stream>>>(u, W1, b1, W2, b2, out);
}

// Round 3
// 77.140 us; speedup vs baseline: 1.2938x; 1.1200x over previous
//
#include <hip/hip_runtime.h>
#include <math.h>

#define HIDDEN 128
#define NGRAPH 16384
#define GPB 32                  // graphs per block
#define NBLK (NGRAPH / GPB)     // 512 blocks

// shifted-softplus shift = log(2)
__device__ __constant__ float kSHIFT = 0.69314718055994530942f;

// ---------------------------------------------------------------------------
// Kernel 0: boundary scan. batch sorted; thread i writes offs[g]=i for every
// graph g starting at i (covers empty graphs). offs[NGRAPH]=n_nodes.
// ---------------------------------------------------------------------------
__global__ __launch_bounds__(256) void offsets_kernel(
    const int* __restrict__ batch, int* __restrict__ offs, int n_nodes)
{
    int i = blockIdx.x * blockDim.x + threadIdx.x;
    if (i >= n_nodes) return;
    int b = batch[i];
    int prev = (i == 0) ? -1 : batch[i - 1];
    for (int g = prev + 1; g <= b; ++g) offs[g] = i;        // rare
    if (i == n_nodes - 1)
        for (int g = b + 1; g <= NGRAPH; ++g) offs[g] = n_nodes;
}

// ---------------------------------------------------------------------------
// Fused kernel: 512 blocks x 256 threads, 32 graphs per block.
// Phase 1: each of the 4 waves streams 8 graphs' node ranges (coalesced
//   float4, 4 accumulators => 4 loads in flight/lane), shfl-reduces across
//   the two wave halves, writes u rows straight into LDS (u never hits HBM).
// Phase 2: 32-row x 256-col MLP tile. acc[4][8] register blocking.
//   u_s reads broadcast (2 addrs/wave); w_s reads conflict-free broadcast.
//   Epilogue: bias -> shifted softplus -> W2 dot -> 32-lane shuffle reduce.
// LDS: 16 KB u_s + 32 KB w_s = 48 KB  -> 2 blocks/CU resident (grid/CU).
// ---------------------------------------------------------------------------
__global__ __launch_bounds__(256, 2) void fused_kernel(
    const float* __restrict__ v, const int* __restrict__ offs,
    const float* __restrict__ W1, const float* __restrict__ b1,
    const float* __restrict__ W2, const float* __restrict__ b2,
    float* __restrict__ out)
{
    __shared__ float u_s[GPB * HIDDEN];   // 16 KB
    __shared__ float w_s[32 * 256];       // 32 KB

    const int t  = threadIdx.x;
    const int l  = t & 63;
    const int w  = t >> 6;                 // wave id 0..3
    const int g0 = blockIdx.x * GPB;

    const int f4 = l & 31;                 // float4 column 0..31
    const int ro = l >> 5;                 // row half 0..1

    const float4* __restrict__ v4 = reinterpret_cast<const float4*>(v);
    float4* u_s4 = reinterpret_cast<float4*>(u_s);

    // ---------------- Phase 1: segment sums into LDS ----------------
    for (int gi = 0; gi < 8; ++gi) {
        const int gl    = w * 8 + gi;              // local graph 0..31
        const int start = offs[g0 + gl];
        const int end   = offs[g0 + gl + 1];

        float4 a0 = make_float4(0.f, 0.f, 0.f, 0.f);
        float4 a1 = a0, a2 = a0, a3 = a0;
        int r = start + ro;
        for (; r + 6 < end; r += 8) {
            float4 x0 = v4[(size_t)r       * 32 + f4];
            float4 x1 = v4[(size_t)(r + 2) * 32 + f4];
            float4 x2 = v4[(size_t)(r + 4) * 32 + f4];
            float4 x3 = v4[(size_t)(r + 6) * 32 + f4];
            a0.x += x0.x; a0.y += x0.y; a0.z += x0.z; a0.w += x0.w;
            a1.x += x1.x; a1.y += x1.y; a1.z += x1.z; a1.w += x1.w;
            a2.x += x2.x; a2.y += x2.y; a2.z += x2.z; a2.w += x2.w;
            a3.x += x3.x; a3.y += x3.y; a3.z += x3.z; a3.w += x3.w;
        }
        for (; r < end; r += 2) {
            float4 x = v4[(size_t)r * 32 + f4];
            a0.x += x.x; a0.y += x.y; a0.z += x.z; a0.w += x.w;
        }
        float4 s;
        s.x = (a0.x + a1.x) + (a2.x + a3.x);
        s.y = (a0.y + a1.y) + (a2.y + a3.y);
        s.z = (a0.z + a1.z) + (a2.z + a3.z);
        s.w = (a0.w + a1.w) + (a2.w + a3.w);
        s.x += __shfl_xor(s.x, 32);
        s.y += __shfl_xor(s.y, 32);
        s.z += __shfl_xor(s.z, 32);
        s.w += __shfl_xor(s.w, 32);
        if (ro == 0) u_s4[gl * 32 + f4] = s;
    }
    __syncthreads();

    // ---------------- Phase 2: MLP on the 32-row tile ----------------
    const int cg = t & 31;   // col group: cols cg + 32j
    const int rg = t >> 5;   // row group: rows rg + 8i

    float acc[4][8];
    #pragma unroll
    for (int i = 0; i < 4; ++i)
        #pragma unroll
        for (int j = 0; j < 8; ++j) acc[i][j] = 0.f;

    const float4* __restrict__ W14 = reinterpret_cast<const float4*>(W1);
    float4* w_s4 = reinterpret_cast<float4*>(w_s);

    for (int kc = 0; kc < 4; ++kc) {
        if (kc) __syncthreads();
        #pragma unroll
        for (int q = 0; q < 8; ++q)
            w_s4[t + 256 * q] = W14[kc * 2048 + t + 256 * q];
        __syncthreads();

        #pragma unroll
        for (int k4 = 0; k4 < 32; k4 += 4) {
            float4 a4[4];
            #pragma unroll
            for (int i = 0; i < 4; ++i)
                a4[i] = *reinterpret_cast<const float4*>(
                    &u_s[(rg + 8 * i) * 128 + kc * 32 + k4]);
            #pragma unroll
            for (int kk = 0; kk < 4; ++kk) {
                float b[8];
                #pragma unroll
                for (int j = 0; j < 8; ++j)
                    b[j] = w_s[(k4 + kk) * 256 + cg + 32 * j];
                #pragma unroll
                for (int i = 0; i < 4; ++i) {
                    float av = (kk == 0) ? a4[i].x : (kk == 1) ? a4[i].y
                             : (kk == 2) ? a4[i].z : a4[i].w;
                    #pragma unroll
                    for (int j = 0; j < 8; ++j)
                        acc[i][j] = fmaf(av, b[j], acc[i][j]);
                }
            }
        }
    }

    // epilogue: bias, shifted softplus, W2 contraction, 32-lane reduce
    const float bias2 = b2[0];
    #pragma unroll
    for (int i = 0; i < 4; ++i) {
        float partial = 0.f;
        #pragma unroll
        for (int j = 0; j < 8; ++j) {
            int c = cg + 32 * j;
            float x = acc[i][j] + b1[c];
            float h = fmaxf(x, 0.f) + log1pf(expf(-fabsf(x))) - kSHIFT;
            partial += h * W2[c];
        }
        #pragma unroll
        for (int m = 16; m >= 1; m >>= 1)
            partial += __shfl_xor(partial, m);
        if (cg == 0)
            out[g0 + rg + 8 * i] = partial + bias2;
    }
}

extern "C" void kernel_launch(void* const* d_in, const int* in_sizes, int n_in,
                              void* d_out, int out_size, void* d_ws, size_t ws_size,
                              hipStream_t stream) {
    const float* v     = (const float*)d_in[0];
    const int*   batch = (const int*)d_in[1];
    const float* W1    = (const float*)d_in[2];
    const float* b1    = (const float*)d_in[3];
    const float* W2    = (const float*)d_in[4];
    const float* b2    = (const float*)d_in[5];
    float* out = (float*)d_out;

    const int n_nodes = in_sizes[0] / HIDDEN;   // 500000
    int* offs = (int*)d_ws;                     // (NGRAPH+1) ints = 64 KB + 4

    offsets_kernel<<<(n_nodes + 255) / 256, 256, 0, stream>>>(batch, offs, n_nodes);
    fused_kernel<<<NBLK, 256, 0, stream>>>(v, offs, W1, b1, W2, b2, out);
}